// Round 5
// baseline (116.140 us; speedup 1.0000x reference)
//
#include <hip/hip_runtime.h>

// Fused WindowRegionDetector, round 5: instruction-count surgery.
//  - P2/P4/P6a: 16-wide aligned groups, group-major order (no divergent
//    shift); short last group masks only the store.
//  - P3: 8-col x 4-row tasks, uint4 reads, v_pk_add_f32 accumulation,
//    mean division folded into fmaf(-1/225, cs, lum).
//  - P5/P6b: pk_add warmup/slides.
// Buffers padded so uniform-path OOB reads stay in-array; junk columns
// provably never reach stored/consumed outputs.
// LDS 52064 B -> 3 blocks/CU.
// Semantics: box15 zero-padded /225 always; d, comb forced 0 outside image;
// avgpool5 count_include_pad /25 always.

#define BLOCK 512
typedef unsigned short u16;
typedef unsigned int u32;
typedef __attribute__((ext_vector_type(2))) float f32x2;

#define SL 104   // sLum u16 stride (208 B)
#define S1 88    // sT1 / sDC u16 stride (176 B)

__device__ __forceinline__ float blo(u32 u){ return __uint_as_float(u << 16); }
__device__ __forceinline__ float bhi(u32 u){ return __uint_as_float(u & 0xffff0000u); }
__device__ __forceinline__ u32 pk2(float lo, float hi){
    u32 r; asm("v_cvt_pk_bf16_f32 %0, %1, %2" : "=v"(r) : "v"(lo), "v"(hi)); return r;
}
__device__ __forceinline__ f32x2 pka(f32x2 a, f32x2 b){
    f32x2 d; asm("v_pk_add_f32 %0, %1, %2" : "=v"(d) : "v"(a), "v"(b)); return d;
}
__device__ __forceinline__ f32x2 up2(u32 u){
    f32x2 r; r.x = __uint_as_float(u << 16); r.y = __uint_as_float(u & 0xffff0000u); return r;
}
__device__ __forceinline__ float sigf(float x){ return 1.f / (1.f + __expf(-x)); }
__device__ __forceinline__ float clamp01(float x){ return fminf(fmaxf(x, 0.f), 1.f); }
__device__ __forceinline__ void unp8(uint4 v, float* o){
    o[0]=blo(v.x); o[1]=bhi(v.x); o[2]=blo(v.y); o[3]=bhi(v.y);
    o[4]=blo(v.z); o[5]=bhi(v.z); o[6]=blo(v.w); o[7]=bhi(v.w);
}
__device__ __forceinline__ float satm(float r_, float g_, float b_){
    float mx = fmaxf(r_, fmaxf(g_, b_));
    float mn = fminf(r_, fminf(g_, b_));
    float sat = (mx - mn) / (mx + 1e-8f);
    return sigf((0.3f - sat) * 10.f);
}

template<bool EDGE>
__device__ __forceinline__ void body(const float* __restrict__ pR,
                                     const float* __restrict__ pG,
                                     const float* __restrict__ pB,
                                     float* __restrict__ po,
                                     int oy, int ox, int tid,
                                     u16* sLum, u16* sT1, u16* sDC)
{
    const float C225 = 1.f / 225.f;
    const float CF   = 50.f / 225.f;

    // ---- P1: lum bf16, 96 rows x 6 groups of 16 cols (576 tasks) ----
    for (int task = tid; task < 96 * 6; task += BLOCK) {
        int r = task / 6, c = task - r * 6;
        int gy = oy - 16 + r;
        int gxb = ox - 16 + 16 * c;
        u32 pk[8];
        #pragma unroll
        for (int sq = 0; sq < 4; ++sq) {
            int gx = gxb + 4 * sq;
            float l0 = 0.f, l1 = 0.f, l2 = 0.f, l3 = 0.f;
            if (!EDGE || ((unsigned)gy < 1024u && (unsigned)gx < 1024u)) {
                int idx = gy * 1024 + gx;
                float4 R  = *(const float4*)&pR[idx];
                float4 G  = *(const float4*)&pG[idx];
                float4 Bc = *(const float4*)&pB[idx];
                l0 = fmaf(0.299f, R.x, fmaf(0.587f, G.x, 0.114f * Bc.x));
                l1 = fmaf(0.299f, R.y, fmaf(0.587f, G.y, 0.114f * Bc.y));
                l2 = fmaf(0.299f, R.z, fmaf(0.587f, G.z, 0.114f * Bc.z));
                l3 = fmaf(0.299f, R.w, fmaf(0.587f, G.w, 0.114f * Bc.w));
            }
            pk[2 * sq]     = pk2(l0, l1);
            pk[2 * sq + 1] = pk2(l2, l3);
        }
        u16* dst = &sLum[r * SL + 16 * c];
        *(uint4*)dst     = make_uint4(pk[0], pk[1], pk[2], pk[3]);
        *(uint4*)(dst+8) = make_uint4(pk[4], pk[5], pk[6], pk[7]);
    }
    __syncthreads();

    // ---- P2: hbox15(lum) -> sT1 bf16; group-major, 6 groups x 96 rows ----
    // groups 0..4: 16 outputs; group 5: 4 outputs (cols 80..83, 82/83 junk)
    for (int task = tid; task < 6 * 96; task += BLOCK) {
        int g = task / 96, r = task - g * 96;
        int s0 = 16 * g;
        const u16* lr = &sLum[r * SL + s0];
        float lv[32];
        unp8(*(const uint4*)lr,        lv);
        unp8(*(const uint4*)(lr + 8),  lv + 8);
        unp8(*(const uint4*)(lr + 16), lv + 16);
        unp8(*(const uint4*)(lr + 24), lv + 24);
        float o[16];
        float s = 0.f;
        #pragma unroll
        for (int k = 0; k < 15; ++k) s += lv[k];
        o[0] = s;
        #pragma unroll
        for (int j = 1; j < 16; ++j) { s += lv[j + 14] - lv[j - 1]; o[j] = s; }
        u16* dst = &sT1[r * S1 + s0];
        if (g < 5) {
            *(uint4*)dst     = make_uint4(pk2(o[0],o[1]), pk2(o[2],o[3]),
                                          pk2(o[4],o[5]), pk2(o[6],o[7]));
            *(uint4*)(dst+8) = make_uint4(pk2(o[8],o[9]),  pk2(o[10],o[11]),
                                          pk2(o[12],o[13]),pk2(o[14],o[15]));
        } else {
            *(uint2*)dst = make_uint2(pk2(o[0],o[1]), pk2(o[2],o[3]));
        }
    }
    __syncthreads();

    // ---- P3: mean via pk-vbox15; d=(lum-mean)^2 bf16 -> sDC ----
    // 21 row-groups of 4 x 11 col-groups of 8 (231 tasks)
    for (int task = tid; task < 231; task += BLOCK) {
        int rg = task / 11, cg = task - rg * 11;
        int r0 = 4 * rg, c0 = 8 * cg;
        const u16* hp = &sT1[r0 * S1 + c0];
        f32x2 cs0, cs1, cs2, cs3;
        f32x2 n00,n01,n02,n03, n10,n11,n12,n13, n20,n21,n22,n23;
        {
            uint4 v = *(const uint4*)hp;
            cs0 = up2(v.x); cs1 = up2(v.y); cs2 = up2(v.z); cs3 = up2(v.w);
            n00 = -cs0; n01 = -cs1; n02 = -cs2; n03 = -cs3;
        }
        {
            uint4 v = *(const uint4*)(hp + S1);
            f32x2 e0 = up2(v.x), e1 = up2(v.y), e2 = up2(v.z), e3 = up2(v.w);
            n10 = -e0; n11 = -e1; n12 = -e2; n13 = -e3;
            cs0 = pka(cs0, e0); cs1 = pka(cs1, e1);
            cs2 = pka(cs2, e2); cs3 = pka(cs3, e3);
        }
        {
            uint4 v = *(const uint4*)(hp + 2 * S1);
            f32x2 e0 = up2(v.x), e1 = up2(v.y), e2 = up2(v.z), e3 = up2(v.w);
            n20 = -e0; n21 = -e1; n22 = -e2; n23 = -e3;
            cs0 = pka(cs0, e0); cs1 = pka(cs1, e1);
            cs2 = pka(cs2, e2); cs3 = pka(cs3, e3);
        }
        #pragma unroll
        for (int k = 3; k < 15; ++k) {
            uint4 v = *(const uint4*)(hp + k * S1);
            cs0 = pka(cs0, up2(v.x)); cs1 = pka(cs1, up2(v.y));
            cs2 = pka(cs2, up2(v.z)); cs3 = pka(cs3, up2(v.w));
        }
        auto emitD = [&](int row) {
            const u16* lrow = &sLum[(row + 7) * SL + c0];
            u32 aw  = *(const u32*)(lrow + 6);      // lum cols c0+6,7
            uint4 bv = *(const uint4*)(lrow + 8);   // lum cols c0+8..15
            float L0 = bhi(aw);
            float L1 = blo(bv.x), L2 = bhi(bv.x);
            float L3 = blo(bv.y), L4 = bhi(bv.y);
            float L5 = blo(bv.z), L6 = bhi(bv.z);
            float L7 = blo(bv.w);
            float t0 = fmaf(-C225, cs0.x, L0), t1 = fmaf(-C225, cs0.y, L1);
            float t2 = fmaf(-C225, cs1.x, L2), t3 = fmaf(-C225, cs1.y, L3);
            float t4 = fmaf(-C225, cs2.x, L4), t5 = fmaf(-C225, cs2.y, L5);
            float t6 = fmaf(-C225, cs3.x, L6), t7 = fmaf(-C225, cs3.y, L7);
            float d0=t0*t0, d1=t1*t1, d2=t2*t2, d3=t3*t3;
            float d4=t4*t4, d5=t5*t5, d6=t6*t6, d7=t7*t7;
            if (EDGE) {
                int gy = oy - 9 + row, gx = ox - 9 + c0;
                bool vy = (unsigned)gy < 1024u;
                d0 = (vy && (unsigned)(gx    ) < 1024u) ? d0 : 0.f;
                d1 = (vy && (unsigned)(gx + 1) < 1024u) ? d1 : 0.f;
                d2 = (vy && (unsigned)(gx + 2) < 1024u) ? d2 : 0.f;
                d3 = (vy && (unsigned)(gx + 3) < 1024u) ? d3 : 0.f;
                d4 = (vy && (unsigned)(gx + 4) < 1024u) ? d4 : 0.f;
                d5 = (vy && (unsigned)(gx + 5) < 1024u) ? d5 : 0.f;
                d6 = (vy && (unsigned)(gx + 6) < 1024u) ? d6 : 0.f;
                d7 = (vy && (unsigned)(gx + 7) < 1024u) ? d7 : 0.f;
            }
            *(uint4*)&sDC[row * S1 + c0] =
                make_uint4(pk2(d0,d1), pk2(d2,d3), pk2(d4,d5), pk2(d6,d7));
        };
        emitD(r0);
        {
            uint4 v = *(const uint4*)(hp + 15 * S1);
            cs0 = pka(pka(cs0, up2(v.x)), n00); cs1 = pka(pka(cs1, up2(v.y)), n01);
            cs2 = pka(pka(cs2, up2(v.z)), n02); cs3 = pka(pka(cs3, up2(v.w)), n03);
        }
        emitD(r0 + 1);
        {
            uint4 v = *(const uint4*)(hp + 16 * S1);
            cs0 = pka(pka(cs0, up2(v.x)), n10); cs1 = pka(pka(cs1, up2(v.y)), n11);
            cs2 = pka(pka(cs2, up2(v.z)), n12); cs3 = pka(pka(cs3, up2(v.w)), n13);
        }
        emitD(r0 + 2);
        {
            uint4 v = *(const uint4*)(hp + 17 * S1);
            cs0 = pka(pka(cs0, up2(v.x)), n20); cs1 = pka(pka(cs1, up2(v.y)), n21);
            cs2 = pka(pka(cs2, up2(v.z)), n22); cs3 = pka(pka(cs3, up2(v.w)), n23);
        }
        emitD(r0 + 3);
    }
    __syncthreads();

    // ---- P4: hbox15(d) -> sT1 bf16; group-major, 5 groups x 82 rows ----
    // groups 0..3: 16 outputs; group 4: 4 outputs (cols 64..67)
    for (int task = tid; task < 5 * 82; task += BLOCK) {
        int g = task / 82, r = task - g * 82;
        int s0 = 16 * g;
        const u16* dr = &sDC[r * S1 + s0];
        float lv[32];
        unp8(*(const uint4*)dr,        lv);
        unp8(*(const uint4*)(dr + 8),  lv + 8);
        unp8(*(const uint4*)(dr + 16), lv + 16);
        unp8(*(const uint4*)(dr + 24), lv + 24);
        float o[16];
        float s = 0.f;
        #pragma unroll
        for (int k = 0; k < 15; ++k) s += lv[k];
        o[0] = s;
        #pragma unroll
        for (int j = 1; j < 16; ++j) { s += lv[j + 14] - lv[j - 1]; o[j] = s; }
        u16* dst = &sT1[r * S1 + s0];
        if (g < 4) {
            *(uint4*)dst     = make_uint4(pk2(o[0],o[1]), pk2(o[2],o[3]),
                                          pk2(o[4],o[5]), pk2(o[6],o[7]));
            *(uint4*)(dst+8) = make_uint4(pk2(o[8],o[9]),  pk2(o[10],o[11]),
                                          pk2(o[12],o[13]),pk2(o[14],o[15]));
        } else {
            *(uint2*)dst = make_uint2(pk2(o[0],o[1]), pk2(o[2],o[3]));
        }
    }
    __syncthreads();

    // ---- P5: var via pk-vbox15; comb bf16 -> sDC (overwrites d) ----
    // 17 row-groups of 4 x 17 col-quads (289 tasks)
    for (int task = tid; task < 289; task += BLOCK) {
        int rg = task / 17, q = task - rg * 17;
        int r0 = 4 * rg, c0 = 4 * q;
        const u16* hp = &sT1[r0 * S1 + c0];
        f32x2 cs0, cs1, n00,n01, n10,n11, n20,n21;
        {
            uint2 v = *(const uint2*)hp;
            cs0 = up2(v.x); cs1 = up2(v.y);
            n00 = -cs0; n01 = -cs1;
        }
        {
            uint2 v = *(const uint2*)(hp + S1);
            f32x2 e0 = up2(v.x), e1 = up2(v.y);
            n10 = -e0; n11 = -e1;
            cs0 = pka(cs0, e0); cs1 = pka(cs1, e1);
        }
        {
            uint2 v = *(const uint2*)(hp + 2 * S1);
            f32x2 e0 = up2(v.x), e1 = up2(v.y);
            n20 = -e0; n21 = -e1;
            cs0 = pka(cs0, e0); cs1 = pka(cs1, e1);
        }
        #pragma unroll
        for (int k = 3; k < 15; ++k) {
            uint2 v = *(const uint2*)(hp + k * S1);
            cs0 = pka(cs0, up2(v.x)); cs1 = pka(cs1, up2(v.y));
        }
        auto emitC = [&](int row) {
            float cm0 = sigf(fmaf(cs0.x, CF, -0.5f));
            float cm1 = sigf(fmaf(cs0.y, CF, -0.5f));
            float cm2 = sigf(fmaf(cs1.x, CF, -0.5f));
            float cm3 = sigf(fmaf(cs1.y, CF, -0.5f));
            const u16* lr = &sLum[(row + 14) * SL + c0 + 14];
            u32 la = *(const u32*)lr;        // lum cols c0+14,15
            u32 lb = *(const u32*)(lr + 2);  // lum cols c0+16,17
            float bm0 = sigf((blo(la) - 0.7f) * 10.f);
            float bm1 = sigf((bhi(la) - 0.7f) * 10.f);
            float bm2 = sigf((blo(lb) - 0.7f) * 10.f);
            float bm3 = sigf((bhi(lb) - 0.7f) * 10.f);
            int gy = oy - 2 + row, gx0 = ox - 2 + c0;
            int i0 = gy * 1024 + gx0;
            float2 z2 = make_float2(0.f, 0.f);
            float2 Ra, Rb, Ga, Gb, Ba, Bb;
            bool va = true, vb = true;
            if (EDGE) {
                bool vy = (unsigned)gy < 1024u;
                va = vy && (unsigned)gx0 < 1024u;
                vb = vy && (unsigned)(gx0 + 2) < 1024u;
                Ra = va ? *(const float2*)&pR[i0]     : z2;
                Rb = vb ? *(const float2*)&pR[i0 + 2] : z2;
                Ga = va ? *(const float2*)&pG[i0]     : z2;
                Gb = vb ? *(const float2*)&pG[i0 + 2] : z2;
                Ba = va ? *(const float2*)&pB[i0]     : z2;
                Bb = vb ? *(const float2*)&pB[i0 + 2] : z2;
            } else {
                Ra = *(const float2*)&pR[i0];  Rb = *(const float2*)&pR[i0 + 2];
                Ga = *(const float2*)&pG[i0];  Gb = *(const float2*)&pG[i0 + 2];
                Ba = *(const float2*)&pB[i0];  Bb = *(const float2*)&pB[i0 + 2];
            }
            float cb0 = clamp01(bm0 + 0.5f * cm0 * satm(Ra.x, Ga.x, Ba.x));
            float cb1 = clamp01(bm1 + 0.5f * cm1 * satm(Ra.y, Ga.y, Ba.y));
            float cb2 = clamp01(bm2 + 0.5f * cm2 * satm(Rb.x, Gb.x, Bb.x));
            float cb3 = clamp01(bm3 + 0.5f * cm3 * satm(Rb.y, Gb.y, Bb.y));
            if (EDGE) {
                cb0 = va ? cb0 : 0.f;  cb1 = va ? cb1 : 0.f;
                cb2 = vb ? cb2 : 0.f;  cb3 = vb ? cb3 : 0.f;
            }
            *(uint2*)&sDC[row * S1 + c0] = make_uint2(pk2(cb0,cb1), pk2(cb2,cb3));
        };
        emitC(r0);
        {
            uint2 v = *(const uint2*)(hp + 15 * S1);
            cs0 = pka(pka(cs0, up2(v.x)), n00); cs1 = pka(pka(cs1, up2(v.y)), n01);
        }
        emitC(r0 + 1);
        {
            uint2 v = *(const uint2*)(hp + 16 * S1);
            cs0 = pka(pka(cs0, up2(v.x)), n10); cs1 = pka(pka(cs1, up2(v.y)), n11);
        }
        emitC(r0 + 2);
        {
            uint2 v = *(const uint2*)(hp + 17 * S1);
            cs0 = pka(pka(cs0, up2(v.x)), n20); cs1 = pka(pka(cs1, up2(v.y)), n21);
        }
        emitC(r0 + 3);
    }
    __syncthreads();

    // ---- P6a: hpool5(comb) -> sT1 bf16; group-major, 4 groups x 68 rows ----
    for (int task = tid; task < 4 * 68; task += BLOCK) {
        int g = task / 68, r = task - g * 68;
        int s0 = 16 * g;
        const u16* cr = &sDC[r * S1 + s0];
        float cv[24];
        unp8(*(const uint4*)cr,        cv);
        unp8(*(const uint4*)(cr + 8),  cv + 8);
        unp8(*(const uint4*)(cr + 16), cv + 16);
        float o[16];
        float s = cv[0] + cv[1] + cv[2] + cv[3] + cv[4];
        o[0] = s;
        #pragma unroll
        for (int j = 1; j < 16; ++j) { s += cv[j + 4] - cv[j - 1]; o[j] = s; }
        u16* dst = &sT1[r * S1 + s0];
        *(uint4*)dst = make_uint4(pk2(o[0], o[1]), pk2(o[2], o[3]),
                                  pk2(o[4], o[5]), pk2(o[6], o[7]));
        *(uint4*)(dst + 8) = make_uint4(pk2(o[8],  o[9]),  pk2(o[10], o[11]),
                                        pk2(o[12], o[13]), pk2(o[14], o[15]));
    }
    __syncthreads();

    // ---- P6b: vpool5 -> out; 16 row-groups of 4 x 16 col-quads (256) ----
    for (int task = tid; task < 256; task += BLOCK) {
        int rg = task >> 4, q = task & 15;
        int r0 = 4 * rg, c0 = 4 * q;
        const u16* hp = &sT1[r0 * S1 + c0];
        f32x2 cs0, cs1, n00,n01, n10,n11, n20,n21;
        {
            uint2 v = *(const uint2*)hp;
            cs0 = up2(v.x); cs1 = up2(v.y);
            n00 = -cs0; n01 = -cs1;
        }
        {
            uint2 v = *(const uint2*)(hp + S1);
            f32x2 e0 = up2(v.x), e1 = up2(v.y);
            n10 = -e0; n11 = -e1;
            cs0 = pka(cs0, e0); cs1 = pka(cs1, e1);
        }
        {
            uint2 v = *(const uint2*)(hp + 2 * S1);
            f32x2 e0 = up2(v.x), e1 = up2(v.y);
            n20 = -e0; n21 = -e1;
            cs0 = pka(cs0, e0); cs1 = pka(cs1, e1);
        }
        {
            uint2 v = *(const uint2*)(hp + 3 * S1);
            cs0 = pka(cs0, up2(v.x)); cs1 = pka(cs1, up2(v.y));
        }
        {
            uint2 v = *(const uint2*)(hp + 4 * S1);
            cs0 = pka(cs0, up2(v.x)); cs1 = pka(cs1, up2(v.y));
        }
        const float C25 = 1.f / 25.f;
        float* o0 = po + (size_t)(oy + r0) * 1024 + ox + c0;
        *(float4*)o0 = make_float4(cs0.x*C25, cs0.y*C25, cs1.x*C25, cs1.y*C25);
        {
            uint2 v = *(const uint2*)(hp + 5 * S1);
            cs0 = pka(pka(cs0, up2(v.x)), n00); cs1 = pka(pka(cs1, up2(v.y)), n01);
        }
        *(float4*)(o0 + 1024) = make_float4(cs0.x*C25, cs0.y*C25, cs1.x*C25, cs1.y*C25);
        {
            uint2 v = *(const uint2*)(hp + 6 * S1);
            cs0 = pka(pka(cs0, up2(v.x)), n10); cs1 = pka(pka(cs1, up2(v.y)), n11);
        }
        *(float4*)(o0 + 2048) = make_float4(cs0.x*C25, cs0.y*C25, cs1.x*C25, cs1.y*C25);
        {
            uint2 v = *(const uint2*)(hp + 7 * S1);
            cs0 = pka(pka(cs0, up2(v.x)), n20); cs1 = pka(pka(cs1, up2(v.y)), n21);
        }
        *(float4*)(o0 + 3072) = make_float4(cs0.x*C25, cs0.y*C25, cs1.x*C25, cs1.y*C25);
    }
}

__global__ __launch_bounds__(BLOCK, 6)
void wrd_kernel(const float* __restrict__ img, float* __restrict__ out) {
    __shared__ u16 sLum[96 * SL + 16];  // 20000 B (pad: g=5 uniform reads)
    __shared__ u16 sT1[98 * S1];        // 17248 B (rows 96,97: P3 rg=20 slides)
    __shared__ u16 sDC[84 * S1 + 16];   // 14816 B (rows 82,83 + pad: junk)

    int bid = blockIdx.x, nwg = gridDim.x;
    int flat = ((nwg & 7) == 0) ? ((bid & 7) * (nwg >> 3) + (bid >> 3)) : bid;
    const int b = flat >> 8;
    const int t = flat & 255;
    const int oy = (t >> 4) * 64, ox = (t & 15) * 64;

    const float* pR = img + (size_t)b * 3145728u;
    const float* pG = pR + 1048576;
    const float* pB = pR + 2097152;
    float* po = out + (size_t)b * 1048576u;

    bool edge = (ox == 0) | (oy == 0) | (ox == 960) | (oy == 960);
    if (edge) body<true >(pR, pG, pB, po, oy, ox, threadIdx.x, sLum, sT1, sDC);
    else      body<false>(pR, pG, pB, po, oy, ox, threadIdx.x, sLum, sT1, sDC);
}

extern "C" void kernel_launch(void* const* d_in, const int* in_sizes, int n_in,
                              void* d_out, int out_size, void* d_ws, size_t ws_size,
                              hipStream_t stream) {
    const float* img = (const float*)d_in[0];
    float* out = (float*)d_out;
    int Bn = in_sizes[0] / (3 * 1024 * 1024);
    int nwg = Bn * 256;
    hipLaunchKernelGGL(wrd_kernel, dim3(nwg), dim3(BLOCK), 0, stream, img, out);
}